// Round 5
// baseline (46348.212 us; speedup 1.0000x reference)
//
#include <hip/hip_runtime.h>
#include <math.h>

#define D 128
#define D2 256
#define STK 48
#define SEQ 128
#define BATCH 32
#define RDPT 12
#define NSYN 64
#define NSEM 128
#define VOC 16384
#define EPSF 1e-6f
#define GB_C 0.8f
#define CG_C 2.0f

struct RParams {
  const int* input_ids;
  const int* prev_syn;
  const int* prev_sem;
  const float* emb_mag;
  const float* emb_phase;
  const float* cell_Wr;
  const float* cell_Wi;
  const float* norm_scale;
  const float* norm_shift;
  const float* modrelu_b;
  const float* VOr;
  const float* VOi;
  const float* halt_W;
  const float* halt_b;
  const float* stk_W;
  const float* stk_b;
  const float* cb_syn;
  const float* cb_sem;
  const float* ctxsyn_W;
  const float* ctxsyn_b;
  const float* ctxsem_W;
  const float* ctxsem_b;
  const float* gate_W;
  const float* gate_b;
  const float* cbT_syn;   // [256][64]
  const float* cbT_sem;   // [256][128]
  const float* cnrm_syn;  // [64]
  const float* cnrm_sem;  // [128]
  const float* gbsig_syn; // [64][64]
  const float* gbsig_sem; // [128][128]
  float* X;
  float* lossp;
};

__device__ __forceinline__ float waveAllSum(float v) {
  #pragma unroll
  for (int m = 32; m; m >>= 1) v += __shfl_xor(v, m);
  return v;
}

// Two independent batch elements per 1024-thread block (half = tid>>9).
// Each half uses R2's proven 512-thread phase mapping.
__global__ __launch_bounds__(1024) void recur_kernel(RParams p) {
  __shared__ float G1[D2 * D];           // gate_W rows 0..255 (128KB, shared RO)
  __shared__ float partr[2][512], parti[2][512];
  __shared__ float xr_[2][D], xi_[2][D], cr_[2][D], ci_[2][D];
  __shared__ float marr[2][D];
  __shared__ float rAiA[2][D2];          // rA|iA during n-loop; zqs during VQ
  __shared__ float zfc[2][D2], rd_[2][D2];
  __shared__ float acc2[2][D2], sl2[2][D2];
  __shared__ float sptr[2][STK], nptrs[2][STK], wms[2][STK];
  __shared__ float sns[D], nsh[D], smb[D], sgb[D];
  __shared__ float scal[2][16];
  __shared__ int icb[2][2];
  __shared__ int ids[2][SEQ];

  const int tid = threadIdx.x;
  const int half = tid >> 9;
  const int htid = tid & 511;
  const int b = (blockIdx.x << 1) | half;
  const int hw = htid >> 6;     // wave index within half (0..7)
  const int l = htid & 63;
  const int j = htid & 127;     // clin column
  const int kq = htid >> 7;     // k-quarter 0..3
  const int k0 = kq * 32;

  // ---- persistent cell weights in registers (64 VGPR)
  float cwr[32], cwi[32];
  #pragma unroll
  for (int kk = 0; kk < 32; ++kk) {
    cwr[kk] = p.cell_Wr[(size_t)(k0 + kk) * D + j];
    cwi[kk] = p.cell_Wi[(size_t)(k0 + kk) * D + j];
  }
  // ---- G1 (gate rows 0..255) -> LDS once, all 1024 threads
  {
    const float4* g4 = (const float4*)p.gate_W;
    float4* l4 = (float4*)G1;
    for (int e = tid; e < D2 * D / 4; e += 1024) l4[e] = g4[e];
  }
  if (tid < D) {
    sns[tid] = p.norm_scale[tid];
    nsh[tid] = p.norm_shift[tid];
    smb[tid] = p.modrelu_b[tid];
    sgb[tid] = p.gate_b[tid];
  }
  if (htid < SEQ) ids[half][htid] = p.input_ids[(size_t)b * SEQ + htid];
  if (htid < STK) sptr[half][htid] = (htid == 0) ? 1.f : 0.f;
  if (htid == 0) { icb[half][0] = p.prev_syn[b]; icb[half][1] = p.prev_sem[b]; }
  const float hb = p.halt_b[0];
  const float sb0 = p.stk_b[0], sb1 = p.stk_b[1], sb2 = p.stk_b[2];

  // stack memory in regs: (dl = htid&255, jh = htid>>8) owns rows jh*24..+23
  float memv[24];
  #pragma unroll
  for (int q = 0; q < 24; ++q) memv[q] = 0.f;
  const int dl = htid & 255, jh = htid >> 8;
  float lossAcc = 0.f;
  __syncthreads();

  for (int t = 0; t < SEQ; ++t) {
    const int id = ids[half][t];
    if (htid < D) {
      float m = p.emb_mag[(size_t)id * D + htid];
      float ph = p.emb_phase[(size_t)id * D + htid];
      float sv, cv;
      sincosf(ph, &sv, &cv);
      xr_[half][htid] = m * cv;
      xi_[half][htid] = m * sv;
    }
    if (htid < D2) { acc2[half][htid] = 0.f; sl2[half][htid] = 0.f; }
    if (htid == 0) scal[half][0] = 1.f;  // rem
    __syncthreads();

    for (int n = 0; n < RDPT; ++n) {
      // ---- phase 1: cell clin partials (register weights, broadcast LDS x)
      {
        const float4* x4r = (const float4*)(&xr_[half][k0]);
        const float4* x4i = (const float4*)(&xi_[half][k0]);
        float a0 = 0.f, a1 = 0.f, a2 = 0.f, a3 = 0.f;
        #pragma unroll
        for (int q = 0; q < 8; ++q) {
          float4 xa = x4r[q];
          float4 xb = x4i[q];
          a0 = fmaf(xa.x, cwr[q*4+0], a0); a0 = fmaf(-xb.x, cwi[q*4+0], a0);
          a1 = fmaf(xb.x, cwr[q*4+0], a1); a1 = fmaf(xa.x, cwi[q*4+0], a1);
          a2 = fmaf(xa.y, cwr[q*4+1], a2); a2 = fmaf(-xb.y, cwi[q*4+1], a2);
          a3 = fmaf(xb.y, cwr[q*4+1], a3); a3 = fmaf(xa.y, cwi[q*4+1], a3);
          a0 = fmaf(xa.z, cwr[q*4+2], a0); a0 = fmaf(-xb.z, cwi[q*4+2], a0);
          a1 = fmaf(xb.z, cwr[q*4+2], a1); a1 = fmaf(xa.z, cwi[q*4+2], a1);
          a2 = fmaf(xa.w, cwr[q*4+3], a2); a2 = fmaf(-xb.w, cwi[q*4+3], a2);
          a3 = fmaf(xb.w, cwr[q*4+3], a3); a3 = fmaf(xa.w, cwi[q*4+3], a3);
        }
        partr[half][htid] = a0 + a2;
        parti[half][htid] = a1 + a3;
      }
      __syncthreads();
      // ---- phase 2: combine + magnitude
      if (htid < D) {
        float rr = partr[half][htid] + partr[half][htid + 128] +
                   partr[half][htid + 256] + partr[half][htid + 384];
        float ii = parti[half][htid] + parti[half][htid + 128] +
                   parti[half][htid + 256] + parti[half][htid + 384];
        rAiA[half][htid] = rr;
        rAiA[half][htid + 128] = ii;
        marr[half][htid] = sqrtf(rr * rr + ii * ii) + EPSF;
      }
      __syncthreads();
      // ---- phase 3: mean/var (first wave of half)
      if (hw == 0) {
        float m0 = marr[half][l], m1 = marr[half][l + 64];
        float s = waveAllSum(m0 + m1);
        float mean = s * (1.f / D);
        float d0 = m0 - mean, d1 = m1 - mean;
        float v = waveAllSum(d0 * d0 + d1 * d1);
        if (l == 0) {
          scal[half][1] = mean;
          scal[half][2] = rsqrtf(v * (1.f / (D - 1)) + EPSF);
        }
      }
      __syncthreads();
      // ---- phase 4: norm + modReLU
      if (htid < D) {
        float m = marr[half][htid];
        float nm = (m - scal[half][1]) * scal[half][2] * sns[htid] + nsh[htid];
        float r_ = nm * rAiA[half][htid] / m;
        float i_ = nm * rAiA[half][htid + 128] / m;
        float nn = sqrtf(r_ * r_ + i_ * i_) + EPSF;
        float sc = fmaxf(nn + smb[htid], 0.f) / nn;
        cr_[half][htid] = r_ * sc;
        ci_[half][htid] = i_ * sc;
      }
      __syncthreads();
      // ---- phase 5: fused v@o clin, VO streamed from L2
      {
        const float* vr = p.VOr + (size_t)k0 * D + j;
        const float* vi = p.VOi + (size_t)k0 * D + j;
        const float* xc = &cr_[half][k0];
        const float* xs = &ci_[half][k0];
        float a0 = 0.f, a1 = 0.f, a2 = 0.f, a3 = 0.f;
        #pragma unroll
        for (int kk = 0; kk < 32; kk += 2) {
          float w0r = vr[(size_t)kk * D], w1r = vr[(size_t)(kk + 1) * D];
          float w0i = vi[(size_t)kk * D], w1i = vi[(size_t)(kk + 1) * D];
          float x0r = xc[kk], x1r = xc[kk + 1];
          float x0i = xs[kk], x1i = xs[kk + 1];
          a0 = fmaf(x0r, w0r, a0); a0 = fmaf(-x0i, w0i, a0);
          a1 = fmaf(x0i, w0r, a1); a1 = fmaf(x0r, w0i, a1);
          a2 = fmaf(x1r, w1r, a2); a2 = fmaf(-x1i, w1i, a2);
          a3 = fmaf(x1i, w1r, a3); a3 = fmaf(x1r, w1i, a3);
        }
        partr[half][htid] = a0 + a2;
        parti[half][htid] = a1 + a3;
      }
      __syncthreads();
      // ---- phase 6: combine -> zfc
      if (htid < D) {
        zfc[half][htid] = partr[half][htid] + partr[half][htid + 128] +
                          partr[half][htid + 256] + partr[half][htid + 384];
        zfc[half][htid + 128] = parti[half][htid] + parti[half][htid + 128] +
                                parti[half][htid + 256] + parti[half][htid + 384];
      }
      __syncthreads();
      // ---- phase 7: halt + ctrl head dots (waves 0-3 of half)
      if (hw < 4) {
        float s = 0.f;
        if (hw == 0) {
          for (int k = l; k < D2; k += 64) s += zfc[half][k] * p.halt_W[k];
        } else {
          const int c = hw - 1;
          for (int k = l; k < D2; k += 64) s += zfc[half][k] * p.stk_W[k * 3 + c];
        }
        s = waveAllSum(s);
        if (l == 0) scal[half][4 + hw] = s;
      }
      __syncthreads();
      // ---- phase 8: scalar softmax + halt bookkeeping
      if (htid == 0) {
        float halt = 1.f / (1.f + expf(-(scal[half][4] + hb)));
        float e0 = scal[half][5] + sb0;
        float e1 = scal[half][6] + sb1;
        float e2 = scal[half][7] + sb2;
        float mx = fmaxf(e0, fmaxf(e1, e2));
        float x0 = expf(e0 - mx), x1 = expf(e1 - mx), x2 = expf(e2 - mx);
        float sm = x0 + x1 + x2;
        scal[half][8] = x0 / sm;
        scal[half][9] = x1 / sm;
        scal[half][10] = x2 / sm;
        float rem = scal[half][0];
        scal[half][3] = (n == RDPT - 1) ? rem : rem * halt;
        scal[half][0] = rem * (1.f - halt);
      }
      __syncthreads();
      // ---- phase 9: stack pointer (first wave of half)
      if (hw == 0) {
        float push = scal[half][8], pop = scal[half][9], noop = scal[half][10];
        float pj = 0.f, pu = 0.f, pd = 0.f;
        if (l < STK) {
          pj = sptr[half][l];
          pu = sptr[half][(l + STK - 1) % STK];
          pd = sptr[half][(l + 1) % STK];
        }
        float np_ = push * pu + pop * pd + noop * pj;
        float wm_ = push * pu;
        float ssum = waveAllSum((l < STK) ? np_ : 0.f);
        float inv = 1.f / (ssum + EPSF);
        if (l < STK) {
          np_ *= inv;
          nptrs[half][l] = np_;
          sptr[half][l] = np_;
          wms[half][l] = wm_;
        }
      }
      __syncthreads();
      // ---- phase 10: stack mem update + read partials (2-acc ILP)
      {
        float zfd = zfc[half][dl];
        float accA = 0.f, accB = 0.f;
        #pragma unroll
        for (int jj = 0; jj < 12; ++jj) {
          const int jr = jh * 24 + jj;
          float wmj = wms[half][jr];
          memv[jj] = wmj * zfd + memv[jj] * (1.f - wmj);
          accA = fmaf(memv[jj], nptrs[half][jr], accA);
        }
        #pragma unroll
        for (int jj = 12; jj < 24; ++jj) {
          const int jr = jh * 24 + jj;
          float wmj = wms[half][jr];
          memv[jj] = wmj * zfd + memv[jj] * (1.f - wmj);
          accB = fmaf(memv[jj], nptrs[half][jr], accB);
        }
        partr[half][htid] = accA + accB;
      }
      __syncthreads();
      // ---- phase 11: rd combine
      if (htid < D2) rd_[half][htid] = partr[half][htid] + partr[half][htid + 256];
      __syncthreads();
      // ---- phase 12: gate partials (4-acc ILP); q<2 from LDS G1, q>=2 from L2
      {
        float g0 = 0.f, g1 = 0.f, g2 = 0.f, g3 = 0.f;
        if (kq < 2) {
          const int kb = kq * 128;
          const float* gl = &G1[(size_t)kb * D + j];
          const float* xv = &zfc[half][kb];
          #pragma unroll 8
          for (int kk = 0; kk < 128; kk += 4) {
            g0 = fmaf(xv[kk + 0], gl[(size_t)(kk + 0) * D], g0);
            g1 = fmaf(xv[kk + 1], gl[(size_t)(kk + 1) * D], g1);
            g2 = fmaf(xv[kk + 2], gl[(size_t)(kk + 2) * D], g2);
            g3 = fmaf(xv[kk + 3], gl[(size_t)(kk + 3) * D], g3);
          }
        } else {
          const int kb = (kq - 2) * 128;
          const float* gp = p.gate_W + (size_t)(D2 + kb) * D + j;
          const float* xv = &rd_[half][kb];
          #pragma unroll 8
          for (int kk = 0; kk < 128; kk += 4) {
            g0 = fmaf(xv[kk + 0], gp[(size_t)(kk + 0) * D], g0);
            g1 = fmaf(xv[kk + 1], gp[(size_t)(kk + 1) * D], g1);
            g2 = fmaf(xv[kk + 2], gp[(size_t)(kk + 2) * D], g2);
            g3 = fmaf(xv[kk + 3], gp[(size_t)(kk + 3) * D], g3);
          }
        }
        partr[half][htid] = (g0 + g1) + (g2 + g3);
      }
      __syncthreads();
      // ---- phase 13: sigmoid gate + gated residual + accumulators
      if (htid < D) {
        float g = partr[half][htid] + partr[half][htid + 128] +
                  partr[half][htid + 256] + partr[half][htid + 384] + sgb[htid];
        g = 1.f / (1.f + expf(-g));
        float pr_ = zfc[half][htid], pi_ = zfc[half][htid + 128];
        float rr_ = rd_[half][htid], ri_ = rd_[half][htid + 128];
        float nzr = (1.f - g) * pr_ + g * pi_ + g * (rr_ - ri_);
        float nzi = (1.f - g) * pi_ - g * pr_ + g * (ri_ + rr_);
        xr_[half][htid] = nzr;
        xi_[half][htid] = nzi;
        float wgt = scal[half][3];
        acc2[half][htid] += wgt * nzr;
        acc2[half][htid + 128] += wgt * nzi;
        sl2[half][htid] += nzr * (1.f / RDPT);
        sl2[half][htid + 128] += nzi * (1.f / RDPT);
      }
      __syncthreads();
    }  // n

    // ---- VQ syn dots: 8 chunks x 32 k over all 512 threads (2-acc)
    {
      const int c = htid & 63, ch = htid >> 6;
      const int kb = ch * 32;
      const float* cb = p.cbT_syn + (size_t)kb * 64 + c;
      const float* cw = p.ctxsyn_W + (size_t)kb * 64 + c;
      const float* zv = &acc2[half][kb];
      float d0 = 0.f, d1 = 0.f, e0 = 0.f, e1 = 0.f;
      #pragma unroll 8
      for (int kk = 0; kk < 32; kk += 2) {
        d0 = fmaf(cb[(size_t)kk * 64], zv[kk], d0);
        e0 = fmaf(cw[(size_t)kk * 64], zv[kk], e0);
        d1 = fmaf(cb[(size_t)(kk + 1) * 64], zv[kk + 1], d1);
        e1 = fmaf(cw[(size_t)(kk + 1) * 64], zv[kk + 1], e1);
      }
      partr[half][ch * 64 + c] = d0 + d1;
      parti[half][ch * 64 + c] = e0 + e1;
    }
    __syncthreads();
    // ---- VQ syn select (first wave of half)
    if (hw == 0) {
      float dot = 0.f, e = p.ctxsyn_b[l];
      #pragma unroll
      for (int ch = 0; ch < 8; ++ch) {
        dot += partr[half][ch * 64 + l];
        e += parti[half][ch * 64 + l];
      }
      float d = p.cnrm_syn[l] - 2.f * dot;
      float m = e;
      #pragma unroll
      for (int mm = 32; mm; mm >>= 1) m = fmaxf(m, __shfl_xor(m, mm));
      float ex = expf(e - m);
      float s = waveAllSum(ex);
      const int pidx = icb[half][0];
      float score = d - p.gbsig_syn[(size_t)pidx * 64 + l] - CG_C * (ex / s);
      float bv = score; int bi = l;
      #pragma unroll
      for (int mm = 32; mm; mm >>= 1) {
        float ov = __shfl_xor(bv, mm); int oi = __shfl_xor(bi, mm);
        if (ov < bv || (ov == bv && oi < bi)) { bv = ov; bi = oi; }
      }
      if (l == 0) icb[half][0] = bi;
    }
    __syncthreads();
    // ---- zq_syn gather (threads<256) + VQ sem dots (all 512, 4 chunks x 64 k)
    if (htid < D2) {
      const int idx = icb[half][0];
      float zqv = p.cb_syn[(size_t)idx * D2 + htid];
      float df = zqv - acc2[half][htid];
      lossAcc += df * df;
      rAiA[half][htid] = zqv;  // zqs
    }
    {
      const int c = htid & 127, ch = htid >> 7;
      const int kb = ch * 64;
      const float* cb = p.cbT_sem + (size_t)kb * 128 + c;
      const float* cw = p.ctxsem_W + (size_t)kb * 128 + c;
      const float* zv = &sl2[half][kb];
      float d0 = 0.f, d1 = 0.f, e0 = 0.f, e1 = 0.f;
      #pragma unroll 8
      for (int kk = 0; kk < 64; kk += 2) {
        d0 = fmaf(cb[(size_t)kk * 128], zv[kk], d0);
        e0 = fmaf(cw[(size_t)kk * 128], zv[kk], e0);
        d1 = fmaf(cb[(size_t)(kk + 1) * 128], zv[kk + 1], d1);
        e1 = fmaf(cw[(size_t)(kk + 1) * 128], zv[kk + 1], e1);
      }
      partr[half][ch * 128 + c] = d0 + d1;
      parti[half][ch * 128 + c] = e0 + e1;
    }
    __syncthreads();
    // ---- VQ sem select (first wave of half)
    if (hw == 0) {
      float dot0 = 0.f, e0 = p.ctxsem_b[l];
      float dot1 = 0.f, e1 = p.ctxsem_b[l + 64];
      #pragma unroll
      for (int ch = 0; ch < 4; ++ch) {
        dot0 += partr[half][ch * 128 + l];       e0 += parti[half][ch * 128 + l];
        dot1 += partr[half][ch * 128 + l + 64];  e1 += parti[half][ch * 128 + l + 64];
      }
      float d0 = p.cnrm_sem[l] - 2.f * dot0;
      float d1 = p.cnrm_sem[l + 64] - 2.f * dot1;
      float m = fmaxf(e0, e1);
      #pragma unroll
      for (int mm = 32; mm; mm >>= 1) m = fmaxf(m, __shfl_xor(m, mm));
      float x0 = expf(e0 - m), x1 = expf(e1 - m);
      float s = waveAllSum(x0 + x1);
      const int pidx = icb[half][1];
      float s0 = d0 - p.gbsig_sem[(size_t)pidx * 128 + l] - CG_C * (x0 / s);
      float s1 = d1 - p.gbsig_sem[(size_t)pidx * 128 + l + 64] - CG_C * (x1 / s);
      float bv = s0; int bi = l;
      if (s1 < bv) { bv = s1; bi = l + 64; }
      #pragma unroll
      for (int mm = 32; mm; mm >>= 1) {
        float ov = __shfl_xor(bv, mm); int oi = __shfl_xor(bi, mm);
        if (ov < bv || (ov == bv && oi < bi)) { bv = ov; bi = oi; }
      }
      if (l == 0) icb[half][1] = bi;
    }
    __syncthreads();
    // ---- zq_sem gather + loss + X write
    if (htid < D2) {
      const int idx = icb[half][1];
      float zqv = p.cb_sem[(size_t)idx * D2 + htid];
      float df = zqv - sl2[half][htid];
      lossAcc += df * df;
      p.X[(size_t)(b * SEQ + t) * D2 + htid] = 0.5f * (rAiA[half][htid] + zqv);
    }
    __syncthreads();
  }  // t

  // ---- per-half loss reduction
  partr[half][htid] = lossAcc;
  __syncthreads();
  if (htid < 256) partr[half][htid] += partr[half][htid + 256];
  __syncthreads();
  if (htid < 128) partr[half][htid] += partr[half][htid + 128];
  __syncthreads();
  if (htid < 64) {
    float v = partr[half][htid] + partr[half][htid + 64];
    v = waveAllSum(v);
    if (htid == 0) p.lossp[b] = v;
  }
}

// VO = V (complex) @ O (complex)
__global__ __launch_bounds__(256) void voprod_kernel(const float* __restrict__ vr,
                                                     const float* __restrict__ vi,
                                                     const float* __restrict__ orr,
                                                     const float* __restrict__ oii,
                                                     float* __restrict__ VOr,
                                                     float* __restrict__ VOi) {
  __shared__ float a_r[D], a_i[D];
  const int k = blockIdx.x;
  const int tid = threadIdx.x;
  if (tid < D) { a_r[tid] = vr[k * D + tid]; a_i[tid] = vi[k * D + tid]; }
  __syncthreads();
  const int m = tid & 127;
  const int half = tid >> 7;
  float acc = 0.f;
  if (half == 0) {
    #pragma unroll 8
    for (int jj = 0; jj < D; ++jj)
      acc += a_r[jj] * orr[jj * D + m] - a_i[jj] * oii[jj * D + m];
    VOr[k * D + m] = acc;
  } else {
    #pragma unroll 8
    for (int jj = 0; jj < D; ++jj)
      acc += a_r[jj] * oii[jj * D + m] + a_i[jj] * orr[jj * D + m];
    VOi[k * D + m] = acc;
  }
}

__global__ void vqprep_kernel(const float* __restrict__ cb_syn,
                              const float* __restrict__ cb_sem,
                              const float* __restrict__ adj_syn,
                              const float* __restrict__ adj_sem,
                              float* __restrict__ cbT_syn,
                              float* __restrict__ cbT_sem,
                              float* __restrict__ cnrm_syn,
                              float* __restrict__ cnrm_sem,
                              float* __restrict__ gbsig_syn,
                              float* __restrict__ gbsig_sem) {
  const int tid = blockIdx.x * 256 + threadIdx.x;
  const int nt = gridDim.x * 256;
  for (int e = tid; e < NSYN * D2; e += nt) {
    int c = e / D2, k = e % D2;
    cbT_syn[k * NSYN + c] = cb_syn[e];
  }
  for (int e = tid; e < NSEM * D2; e += nt) {
    int c = e / D2, k = e % D2;
    cbT_sem[k * NSEM + c] = cb_sem[e];
  }
  for (int c = tid; c < NSYN; c += nt) {
    float s = 0.f;
    for (int k = 0; k < D2; ++k) { float v = cb_syn[c * D2 + k]; s += v * v; }
    cnrm_syn[c] = s;
  }
  for (int c = tid; c < NSEM; c += nt) {
    float s = 0.f;
    for (int k = 0; k < D2; ++k) { float v = cb_sem[c * D2 + k]; s += v * v; }
    cnrm_sem[c] = s;
  }
  for (int e = tid; e < NSYN * NSYN; e += nt)
    gbsig_syn[e] = GB_C / (1.f + expf(-adj_syn[e]));
  for (int e = tid; e < NSEM * NSEM; e += nt)
    gbsig_sem[e] = GB_C / (1.f + expf(-adj_sem[e]));
}

// logits = X @ dec_W + dec_b
__global__ __launch_bounds__(256) void dec_kernel(const float* __restrict__ X,
                                                  const float* __restrict__ W,
                                                  const float* __restrict__ bias,
                                                  float* __restrict__ out) {
  __shared__ float A[32][D2];
  const int tid = threadIdx.x;
  const int bx = blockIdx.x;
  const int by = blockIdx.y;
  const float* xr = X + (size_t)by * 32 * D2;
  #pragma unroll
  for (int s = 0; s < 32; ++s) A[s][tid] = xr[s * D2 + tid];
  __syncthreads();
  const int ty = tid >> 5, tx = tid & 31;
  const int col0 = bx * 128 + tx * 4;
  const int r0 = ty * 4;
  float acc[4][4];
  #pragma unroll
  for (int r = 0; r < 4; ++r) {
    acc[r][0] = 0.f; acc[r][1] = 0.f; acc[r][2] = 0.f; acc[r][3] = 0.f;
  }
  const float* wp = W + col0;
  for (int k = 0; k < D2; k += 4) {
    float4 w0 = *(const float4*)(wp + (size_t)(k + 0) * VOC);
    float4 w1 = *(const float4*)(wp + (size_t)(k + 1) * VOC);
    float4 w2 = *(const float4*)(wp + (size_t)(k + 2) * VOC);
    float4 w3 = *(const float4*)(wp + (size_t)(k + 3) * VOC);
    #pragma unroll
    for (int r = 0; r < 4; ++r) {
      float4 a = *(const float4*)&A[r0 + r][k];
      acc[r][0] += a.x * w0.x + a.y * w1.x + a.z * w2.x + a.w * w3.x;
      acc[r][1] += a.x * w0.y + a.y * w1.y + a.z * w2.y + a.w * w3.y;
      acc[r][2] += a.x * w0.z + a.y * w1.z + a.z * w2.z + a.w * w3.z;
      acc[r][3] += a.x * w0.w + a.y * w1.w + a.z * w2.w + a.w * w3.w;
    }
  }
  float4 bv = *(const float4*)(bias + col0);
  #pragma unroll
  for (int r = 0; r < 4; ++r) {
    float4 o;
    o.x = acc[r][0] + bv.x; o.y = acc[r][1] + bv.y;
    o.z = acc[r][2] + bv.z; o.w = acc[r][3] + bv.w;
    *(float4*)(out + (size_t)(by * 32 + r0 + r) * VOC + col0) = o;
  }
}

__global__ void loss_kernel(const float* __restrict__ lp, float* __restrict__ out) {
  int l = threadIdx.x;
  float v = (l < BATCH) ? lp[l] : 0.f;
  #pragma unroll
  for (int off = 32; off; off >>= 1) v += __shfl_down(v, off);
  if (l == 0) out[0] = v * (1.25f / 8192.f);
}

extern "C" void kernel_launch(void* const* d_in, const int* in_sizes, int n_in,
                              void* d_out, int out_size, void* d_ws,
                              size_t ws_size, hipStream_t stream) {
  float* ws = (float*)d_ws;
  float* X = ws;                      // 1048576
  float* lossp = X + 1048576;         // 64
  float* VOr = lossp + 64;            // 16384
  float* VOi = VOr + 16384;           // 16384
  float* cbT_syn = VOi + 16384;       // 16384
  float* cbT_sem = cbT_syn + 16384;   // 32768
  float* cnrm_syn = cbT_sem + 32768;  // 64
  float* cnrm_sem = cnrm_syn + 64;    // 128
  float* gbsig_syn = cnrm_sem + 128;  // 4096
  float* gbsig_sem = gbsig_syn + 4096;// 16384

  RParams p;
  p.input_ids  = (const int*)d_in[0];
  p.prev_syn   = (const int*)d_in[1];
  p.prev_sem   = (const int*)d_in[2];
  p.emb_mag    = (const float*)d_in[3];
  p.emb_phase  = (const float*)d_in[4];
  p.cell_Wr    = (const float*)d_in[5];
  p.cell_Wi    = (const float*)d_in[6];
  p.norm_scale = (const float*)d_in[7];
  p.norm_shift = (const float*)d_in[8];
  p.modrelu_b  = (const float*)d_in[9];
  p.VOr        = VOr;
  p.VOi        = VOi;
  p.halt_W     = (const float*)d_in[18];
  p.halt_b     = (const float*)d_in[19];
  p.stk_W      = (const float*)d_in[20];
  p.stk_b      = (const float*)d_in[21];
  p.cb_syn     = (const float*)d_in[22];
  p.cb_sem     = (const float*)d_in[23];
  p.ctxsyn_W   = (const float*)d_in[24];
  p.ctxsyn_b   = (const float*)d_in[25];
  p.ctxsem_W   = (const float*)d_in[26];
  p.ctxsem_b   = (const float*)d_in[27];
  p.gate_W     = (const float*)d_in[30];
  p.gate_b     = (const float*)d_in[31];
  const float* dec_W = (const float*)d_in[32];
  const float* dec_b = (const float*)d_in[33];
  p.cbT_syn = cbT_syn;
  p.cbT_sem = cbT_sem;
  p.cnrm_syn = cnrm_syn;
  p.cnrm_sem = cnrm_sem;
  p.gbsig_syn = gbsig_syn;
  p.gbsig_sem = gbsig_sem;
  p.X = X;
  p.lossp = lossp;

  float* out = (float*)d_out;

  voprod_kernel<<<D, 256, 0, stream>>>((const float*)d_in[14], (const float*)d_in[15],
                                       (const float*)d_in[16], (const float*)d_in[17],
                                       VOr, VOi);
  vqprep_kernel<<<64, 256, 0, stream>>>((const float*)d_in[22], (const float*)d_in[23],
                                        (const float*)d_in[28], (const float*)d_in[29],
                                        cbT_syn, cbT_sem, cnrm_syn, cnrm_sem,
                                        gbsig_syn, gbsig_sem);
  recur_kernel<<<BATCH / 2, 1024, 0, stream>>>(p);
  dec_kernel<<<dim3(VOC / 128, BATCH * SEQ / 32), 256, 0, stream>>>(X, dec_W,
                                                                    dec_b, out);
  loss_kernel<<<1, 64, 0, stream>>>(lossp, out + (size_t)BATCH * SEQ * VOC);
}

// Round 6
// 16737.209 us; speedup vs baseline: 2.7692x; 2.7692x over previous
//
#include <hip/hip_runtime.h>
#include <math.h>

#define D 128
#define D2 256
#define STK 48
#define SEQ 128
#define BATCH 32
#define RDPT 12
#define NSYN 64
#define NSEM 128
#define VOC 16384
#define EPSF 1e-6f
#define GB_C 0.8f
#define CG_C 2.0f

struct RParams {
  const int* input_ids;
  const int* prev_syn;
  const int* prev_sem;
  const float* emb_mag;
  const float* emb_phase;
  const float* cell_Wr;
  const float* cell_Wi;
  const float* norm_scale;
  const float* norm_shift;
  const float* modrelu_b;
  const float* VOr;
  const float* VOi;
  const float* halt_W;
  const float* halt_b;
  const float* stk_W;
  const float* stk_b;
  const float* cb_syn;
  const float* cb_sem;
  const float* ctxsyn_W;
  const float* ctxsyn_b;
  const float* ctxsem_W;
  const float* ctxsem_b;
  const float* gate_W;
  const float* gate_b;
  const float* cbT_syn;   // [256][64]
  const float* cbT_sem;   // [256][128]
  const float* cnrm_syn;  // [64]
  const float* cnrm_sem;  // [128]
  const float* gbsig_syn; // [64][64]
  const float* gbsig_sem; // [128][128]
  float* X;
  float* lossp;
};

__device__ __forceinline__ float waveAllSum(float v) {
  #pragma unroll
  for (int m = 32; m; m >>= 1) v += __shfl_xor(v, m);
  return v;
}

__global__ __launch_bounds__(512, 2) void recur_kernel(RParams p) {
  __shared__ float2 VO2[D * D];                      // [k][j] (r,i) 128KB
  __shared__ float partr[512], parti[512];
  __shared__ alignas(16) float xr_[D], xi_[D], cr_[D], ci_[D];
  __shared__ float rAiA[D2], marr[D];
  __shared__ alignas(16) float zfc[D2], rd_[D2];
  __shared__ alignas(16) float acc2[D2], sl2[D2];
  __shared__ float zqs[D2];
  __shared__ float sptr[STK];
  __shared__ alignas(16) float nptrs[STK], wms[STK];
  __shared__ float scal[16];
  __shared__ int icb[2];
  __shared__ int ids[SEQ];

  const int tid = threadIdx.x;
  const int b = blockIdx.x;
  const int wv = tid >> 6;
  const int l = tid & 63;
  const int j = tid & 127;
  const int kq = tid >> 7;
  const int k0 = kq * 32;

  // ---- persistent cell weights (64 VGPR)
  float cwr[32], cwi[32];
  #pragma unroll
  for (int kk = 0; kk < 32; ++kk) {
    cwr[kk] = p.cell_Wr[(size_t)(k0 + kk) * D + j];
    cwi[kk] = p.cell_Wi[(size_t)(k0 + kk) * D + j];
  }
  // ---- persistent gate weights (128 VGPR): rows kq*128..+127, column j
  float gw[128];
  #pragma unroll
  for (int kk = 0; kk < 128; ++kk)
    gw[kk] = p.gate_W[(size_t)(kq * 128 + kk) * D + j];
  // ---- VO (r,i interleaved) -> LDS
  {
    const float4* r4p = (const float4*)p.VOr;
    const float4* i4p = (const float4*)p.VOi;
    float4* dst = (float4*)VO2;
    for (int e = tid; e < D * D / 4; e += 512) {
      float4 r4 = r4p[e];
      float4 i4 = i4p[e];
      float4 lo, hi;
      lo.x = r4.x; lo.y = i4.x; lo.z = r4.y; lo.w = i4.y;
      hi.x = r4.z; hi.y = i4.z; hi.z = r4.w; hi.w = i4.w;
      dst[e * 2 + 0] = lo;
      dst[e * 2 + 1] = hi;
    }
  }
  // ---- per-thread params in regs
  float snsR = 0.f, nshR = 0.f, smbR = 0.f, sgbR = 0.f;
  if (tid < D) {
    snsR = p.norm_scale[tid];
    nshR = p.norm_shift[tid];
    smbR = p.modrelu_b[tid];
    sgbR = p.gate_b[tid];
  }
  float hwr0 = 0.f, hwr1 = 0.f, hwr2 = 0.f, hwr3 = 0.f;
  if (wv == 0) {
    hwr0 = p.halt_W[l]; hwr1 = p.halt_W[l + 64];
    hwr2 = p.halt_W[l + 128]; hwr3 = p.halt_W[l + 192];
  } else if (wv < 4) {
    const int c = wv - 1;
    hwr0 = p.stk_W[l * 3 + c]; hwr1 = p.stk_W[(l + 64) * 3 + c];
    hwr2 = p.stk_W[(l + 128) * 3 + c]; hwr3 = p.stk_W[(l + 192) * 3 + c];
  }
  if (tid < SEQ) ids[tid] = p.input_ids[(size_t)b * SEQ + tid];
  if (tid < STK) sptr[tid] = (tid == 0) ? 1.f : 0.f;
  if (tid == 0) { icb[0] = p.prev_syn[b]; icb[1] = p.prev_sem[b]; }
  const float hb = p.halt_b[0];
  const float sb0 = p.stk_b[0], sb1 = p.stk_b[1], sb2 = p.stk_b[2];

  // stack memory in regs: (mdl = tid&255, mjh = tid>>8) rows mjh*24..+23
  float memv[24];
  #pragma unroll
  for (int q = 0; q < 24; ++q) memv[q] = 0.f;
  const int mdl = tid & 255, mjh = tid >> 8;
  float lossAcc = 0.f;
  __syncthreads();

  for (int t = 0; t < SEQ; ++t) {
    const int id = ids[t];
    if (tid < D) {
      float m = p.emb_mag[(size_t)id * D + tid];
      float ph = p.emb_phase[(size_t)id * D + tid];
      float sv, cv;
      sincosf(ph, &sv, &cv);
      xr_[tid] = m * cv;
      xi_[tid] = m * sv;
    }
    float remv = 1.f;                       // wave0-uniform
    float accR = 0.f, accI = 0.f, slR = 0.f, slI = 0.f;  // tid<128
    __syncthreads();

    for (int n = 0; n < RDPT; ++n) {
      // ---- p1: cell clin partials (reg weights, float4 broadcast x)
      {
        const float4* x4r = (const float4*)(&xr_[k0]);
        const float4* x4i = (const float4*)(&xi_[k0]);
        float a0 = 0.f, a1 = 0.f, a2 = 0.f, a3 = 0.f;
        #pragma unroll
        for (int q = 0; q < 8; ++q) {
          float4 xa = x4r[q];
          float4 xb = x4i[q];
          a0 = fmaf(xa.x, cwr[q*4+0], a0); a0 = fmaf(-xb.x, cwi[q*4+0], a0);
          a1 = fmaf(xb.x, cwr[q*4+0], a1); a1 = fmaf(xa.x, cwi[q*4+0], a1);
          a2 = fmaf(xa.y, cwr[q*4+1], a2); a2 = fmaf(-xb.y, cwi[q*4+1], a2);
          a3 = fmaf(xb.y, cwr[q*4+1], a3); a3 = fmaf(xa.y, cwi[q*4+1], a3);
          a0 = fmaf(xa.z, cwr[q*4+2], a0); a0 = fmaf(-xb.z, cwi[q*4+2], a0);
          a1 = fmaf(xb.z, cwr[q*4+2], a1); a1 = fmaf(xa.z, cwi[q*4+2], a1);
          a2 = fmaf(xa.w, cwr[q*4+3], a2); a2 = fmaf(-xb.w, cwi[q*4+3], a2);
          a3 = fmaf(xb.w, cwr[q*4+3], a3); a3 = fmaf(xa.w, cwi[q*4+3], a3);
        }
        partr[tid] = a0 + a2;
        parti[tid] = a1 + a3;
      }
      __syncthreads();
      // ---- p2: combine + magnitude
      if (tid < D) {
        float rr = partr[tid] + partr[tid + 128] + partr[tid + 256] + partr[tid + 384];
        float ii = parti[tid] + parti[tid + 128] + parti[tid + 256] + parti[tid + 384];
        rAiA[tid] = rr;
        rAiA[tid + 128] = ii;
        marr[tid] = sqrtf(rr * rr + ii * ii) + EPSF;
      }
      __syncthreads();
      // ---- p3: mean/var (wave 0)
      if (tid < 64) {
        float m0 = marr[l], m1 = marr[l + 64];
        float s = waveAllSum(m0 + m1);
        float mean = s * (1.f / D);
        float d0 = m0 - mean, d1 = m1 - mean;
        float v = waveAllSum(d0 * d0 + d1 * d1);
        if (l == 0) {
          scal[1] = mean;
          scal[2] = rsqrtf(v * (1.f / (D - 1)) + EPSF);
        }
      }
      __syncthreads();
      // ---- p4: norm + modReLU (reg params)
      if (tid < D) {
        float m = marr[tid];
        float nm = (m - scal[1]) * scal[2] * snsR + nshR;
        float r_ = nm * rAiA[tid] / m;
        float i_ = nm * rAiA[tid + 128] / m;
        float nn = sqrtf(r_ * r_ + i_ * i_) + EPSF;
        float sc = fmaxf(nn + smbR, 0.f) / nn;
        cr_[tid] = r_ * sc;
        ci_[tid] = i_ * sc;
      }
      __syncthreads();
      // ---- p5: fused v@o clin: VO from LDS float2, x float4 broadcast
      {
        const float4* c4r = (const float4*)(&cr_[k0]);
        const float4* c4i = (const float4*)(&ci_[k0]);
        float a0 = 0.f, a1 = 0.f, a2 = 0.f, a3 = 0.f;
        #pragma unroll
        for (int q = 0; q < 8; ++q) {
          float4 xa = c4r[q];
          float4 xb = c4i[q];
          const int kb = k0 + q * 4;
          float2 w0 = VO2[(size_t)(kb + 0) * D + j];
          float2 w1 = VO2[(size_t)(kb + 1) * D + j];
          float2 w2 = VO2[(size_t)(kb + 2) * D + j];
          float2 w3 = VO2[(size_t)(kb + 3) * D + j];
          a0 = fmaf(xa.x, w0.x, a0); a0 = fmaf(-xb.x, w0.y, a0);
          a1 = fmaf(xb.x, w0.x, a1); a1 = fmaf(xa.x, w0.y, a1);
          a2 = fmaf(xa.y, w1.x, a2); a2 = fmaf(-xb.y, w1.y, a2);
          a3 = fmaf(xb.y, w1.x, a3); a3 = fmaf(xa.y, w1.y, a3);
          a0 = fmaf(xa.z, w2.x, a0); a0 = fmaf(-xb.z, w2.y, a0);
          a1 = fmaf(xb.z, w2.x, a1); a1 = fmaf(xa.z, w2.y, a1);
          a2 = fmaf(xa.w, w3.x, a2); a2 = fmaf(-xb.w, w3.y, a2);
          a3 = fmaf(xb.w, w3.x, a3); a3 = fmaf(xa.w, w3.y, a3);
        }
        partr[tid] = a0 + a2;
        parti[tid] = a1 + a3;
      }
      __syncthreads();
      // ---- p6: combine -> zfc
      if (tid < D) {
        zfc[tid] = partr[tid] + partr[tid + 128] + partr[tid + 256] + partr[tid + 384];
        zfc[tid + 128] = parti[tid] + parti[tid + 128] + parti[tid + 256] + parti[tid + 384];
      }
      __syncthreads();
      // ---- p7: halt + ctrl head dots (waves 0-3, reg weights)
      if (tid < 256) {
        float s = zfc[l] * hwr0 + zfc[l + 64] * hwr1 +
                  zfc[l + 128] * hwr2 + zfc[l + 192] * hwr3;
        s = waveAllSum(s);
        if (l == 0) scal[4 + wv] = s;
      }
      __syncthreads();
      // ---- p9: wave0: softmax + halt bookkeeping + stack pointer
      if (tid < 64) {
        float halt = 1.f / (1.f + expf(-(scal[4] + hb)));
        float e0 = scal[5] + sb0, e1 = scal[6] + sb1, e2 = scal[7] + sb2;
        float mx = fmaxf(e0, fmaxf(e1, e2));
        float x0 = expf(e0 - mx), x1 = expf(e1 - mx), x2 = expf(e2 - mx);
        float sm = x0 + x1 + x2;
        float push = x0 / sm, pop = x1 / sm, noop = x2 / sm;
        float wgt = (n == RDPT - 1) ? remv : remv * halt;
        if (l == 0) scal[3] = wgt;
        remv = remv * (1.f - halt);
        float pj = 0.f, pu = 0.f, pd = 0.f;
        if (l < STK) {
          pj = sptr[l];
          pu = sptr[(l + STK - 1) % STK];
          pd = sptr[(l + 1) % STK];
        }
        float np_ = push * pu + pop * pd + noop * pj;
        float wm_ = push * pu;
        float ssum = waveAllSum((l < STK) ? np_ : 0.f);
        float inv = 1.f / (ssum + EPSF);
        if (l < STK) {
          np_ *= inv;
          nptrs[l] = np_;
          sptr[l] = np_;
          wms[l] = wm_;
        }
      }
      __syncthreads();
      // ---- p10: stack mem update + read partials (float4 broadcasts)
      {
        const float4* wm4 = (const float4*)wms;
        const float4* np4 = (const float4*)nptrs;
        float zfd = zfc[mdl];
        float accA = 0.f, accB = 0.f;
        #pragma unroll
        for (int m4 = 0; m4 < 6; ++m4) {
          float4 wmv = wm4[mjh * 6 + m4];
          float4 npv = np4[mjh * 6 + m4];
          const int base = m4 * 4;
          memv[base + 0] = wmv.x * zfd + memv[base + 0] * (1.f - wmv.x);
          accA = fmaf(memv[base + 0], npv.x, accA);
          memv[base + 1] = wmv.y * zfd + memv[base + 1] * (1.f - wmv.y);
          accB = fmaf(memv[base + 1], npv.y, accB);
          memv[base + 2] = wmv.z * zfd + memv[base + 2] * (1.f - wmv.z);
          accA = fmaf(memv[base + 2], npv.z, accA);
          memv[base + 3] = wmv.w * zfd + memv[base + 3] * (1.f - wmv.w);
          accB = fmaf(memv[base + 3], npv.w, accB);
        }
        partr[tid] = accA + accB;
      }
      __syncthreads();
      // ---- p11: rd combine
      if (tid < D2) rd_[tid] = partr[tid] + partr[tid + 256];
      __syncthreads();
      // ---- p12: gate partials (reg weights, float4 broadcast src)
      {
        const float4* src4 = (kq < 2) ? (const float4*)(&zfc[kq * 128])
                                      : (const float4*)(&rd_[(kq - 2) * 128]);
        float g0 = 0.f, g1 = 0.f, g2 = 0.f, g3 = 0.f;
        #pragma unroll
        for (int q = 0; q < 32; ++q) {
          float4 xv = src4[q];
          g0 = fmaf(xv.x, gw[q * 4 + 0], g0);
          g1 = fmaf(xv.y, gw[q * 4 + 1], g1);
          g2 = fmaf(xv.z, gw[q * 4 + 2], g2);
          g3 = fmaf(xv.w, gw[q * 4 + 3], g3);
        }
        partr[tid] = (g0 + g1) + (g2 + g3);
      }
      __syncthreads();
      // ---- p13: sigmoid gate + gated residual + reg accumulators
      if (tid < D) {
        float g = partr[tid] + partr[tid + 128] + partr[tid + 256] +
                  partr[tid + 384] + sgbR;
        g = 1.f / (1.f + expf(-g));
        float pr_ = zfc[tid], pi_ = zfc[tid + 128];
        float rr_ = rd_[tid], ri_ = rd_[tid + 128];
        float nzr = (1.f - g) * pr_ + g * pi_ + g * (rr_ - ri_);
        float nzi = (1.f - g) * pi_ - g * pr_ + g * (ri_ + rr_);
        xr_[tid] = nzr;
        xi_[tid] = nzi;
        float wgt = scal[3];
        accR += wgt * nzr;
        accI += wgt * nzi;
        slR += nzr * (1.f / RDPT);
        slI += nzi * (1.f / RDPT);
      }
      __syncthreads();
    }  // n

    // ---- flush accumulators to LDS once per t
    if (tid < D) {
      acc2[tid] = accR; acc2[tid + 128] = accI;
      sl2[tid] = slR;  sl2[tid + 128] = slI;
    }
    __syncthreads();

    // ---- VQ syn dots: 8 chunks x 32 k (float4 broadcast src)
    {
      const int c = tid & 63, ch = tid >> 6;
      const int kb = ch * 32;
      const float* cb = p.cbT_syn + (size_t)kb * 64 + c;
      const float* cw = p.ctxsyn_W + (size_t)kb * 64 + c;
      const float4* a4 = (const float4*)(&acc2[kb]);
      float d0 = 0.f, d1 = 0.f, e0 = 0.f, e1 = 0.f;
      #pragma unroll
      for (int q = 0; q < 8; ++q) {
        float4 zv = a4[q];
        d0 = fmaf(cb[(size_t)(q * 4 + 0) * 64], zv.x, d0);
        e0 = fmaf(cw[(size_t)(q * 4 + 0) * 64], zv.x, e0);
        d1 = fmaf(cb[(size_t)(q * 4 + 1) * 64], zv.y, d1);
        e1 = fmaf(cw[(size_t)(q * 4 + 1) * 64], zv.y, e1);
        d0 = fmaf(cb[(size_t)(q * 4 + 2) * 64], zv.z, d0);
        e0 = fmaf(cw[(size_t)(q * 4 + 2) * 64], zv.z, e0);
        d1 = fmaf(cb[(size_t)(q * 4 + 3) * 64], zv.w, d1);
        e1 = fmaf(cw[(size_t)(q * 4 + 3) * 64], zv.w, e1);
      }
      partr[ch * 64 + c] = d0 + d1;
      parti[ch * 64 + c] = e0 + e1;
    }
    __syncthreads();
    // ---- VQ syn select (wave 0)
    if (tid < 64) {
      float dot = 0.f, e = p.ctxsyn_b[l];
      #pragma unroll
      for (int ch = 0; ch < 8; ++ch) {
        dot += partr[ch * 64 + l];
        e += parti[ch * 64 + l];
      }
      float d = p.cnrm_syn[l] - 2.f * dot;
      float m = e;
      #pragma unroll
      for (int mm = 32; mm; mm >>= 1) m = fmaxf(m, __shfl_xor(m, mm));
      float ex = expf(e - m);
      float s = waveAllSum(ex);
      const int pidx = icb[0];
      float score = d - p.gbsig_syn[(size_t)pidx * 64 + l] - CG_C * (ex / s);
      float bv = score; int bi = l;
      #pragma unroll
      for (int mm = 32; mm; mm >>= 1) {
        float ov = __shfl_xor(bv, mm); int oi = __shfl_xor(bi, mm);
        if (ov < bv || (ov == bv && oi < bi)) { bv = ov; bi = oi; }
      }
      if (l == 0) icb[0] = bi;
    }
    __syncthreads();
    // ---- zq_syn gather + VQ sem dots (4 chunks x 64 k)
    if (tid < D2) {
      const int idx = icb[0];
      float zqv = p.cb_syn[(size_t)idx * D2 + tid];
      float df = zqv - acc2[tid];
      lossAcc += df * df;
      zqs[tid] = zqv;
    }
    {
      const int c = tid & 127, ch = tid >> 7;
      const int kb = ch * 64;
      const float* cb = p.cbT_sem + (size_t)kb * 128 + c;
      const float* cw = p.ctxsem_W + (size_t)kb * 128 + c;
      const float4* a4 = (const float4*)(&sl2[kb]);
      float d0 = 0.f, d1 = 0.f, e0 = 0.f, e1 = 0.f;
      #pragma unroll
      for (int q = 0; q < 16; ++q) {
        float4 zv = a4[q];
        d0 = fmaf(cb[(size_t)(q * 4 + 0) * 128], zv.x, d0);
        e0 = fmaf(cw[(size_t)(q * 4 + 0) * 128], zv.x, e0);
        d1 = fmaf(cb[(size_t)(q * 4 + 1) * 128], zv.y, d1);
        e1 = fmaf(cw[(size_t)(q * 4 + 1) * 128], zv.y, e1);
        d0 = fmaf(cb[(size_t)(q * 4 + 2) * 128], zv.z, d0);
        e0 = fmaf(cw[(size_t)(q * 4 + 2) * 128], zv.z, e0);
        d1 = fmaf(cb[(size_t)(q * 4 + 3) * 128], zv.w, d1);
        e1 = fmaf(cw[(size_t)(q * 4 + 3) * 128], zv.w, e1);
      }
      partr[ch * 128 + c] = d0 + d1;
      parti[ch * 128 + c] = e0 + e1;
    }
    __syncthreads();
    // ---- VQ sem select (wave 0)
    if (tid < 64) {
      float dot0 = 0.f, e0 = p.ctxsem_b[l];
      float dot1 = 0.f, e1 = p.ctxsem_b[l + 64];
      #pragma unroll
      for (int ch = 0; ch < 4; ++ch) {
        dot0 += partr[ch * 128 + l];       e0 += parti[ch * 128 + l];
        dot1 += partr[ch * 128 + l + 64];  e1 += parti[ch * 128 + l + 64];
      }
      float d0 = p.cnrm_sem[l] - 2.f * dot0;
      float d1 = p.cnrm_sem[l + 64] - 2.f * dot1;
      float m = fmaxf(e0, e1);
      #pragma unroll
      for (int mm = 32; mm; mm >>= 1) m = fmaxf(m, __shfl_xor(m, mm));
      float x0 = expf(e0 - m), x1 = expf(e1 - m);
      float s = waveAllSum(x0 + x1);
      const int pidx = icb[1];
      float s0 = d0 - p.gbsig_sem[(size_t)pidx * 128 + l] - CG_C * (x0 / s);
      float s1 = d1 - p.gbsig_sem[(size_t)pidx * 128 + l + 64] - CG_C * (x1 / s);
      float bv = s0; int bi = l;
      if (s1 < bv) { bv = s1; bi = l + 64; }
      #pragma unroll
      for (int mm = 32; mm; mm >>= 1) {
        float ov = __shfl_xor(bv, mm); int oi = __shfl_xor(bi, mm);
        if (ov < bv || (ov == bv && oi < bi)) { bv = ov; bi = oi; }
      }
      if (l == 0) icb[1] = bi;
    }
    __syncthreads();
    // ---- zq_sem gather + loss + X write
    if (tid < D2) {
      const int idx = icb[1];
      float zqv = p.cb_sem[(size_t)idx * D2 + tid];
      float df = zqv - sl2[tid];
      lossAcc += df * df;
      p.X[(size_t)(b * SEQ + t) * D2 + tid] = 0.5f * (zqs[tid] + zqv);
    }
    __syncthreads();
  }  // t

  // ---- block loss reduction
  partr[tid] = lossAcc;
  __syncthreads();
  if (tid < 256) partr[tid] += partr[tid + 256];
  __syncthreads();
  if (tid < 128) partr[tid] += partr[tid + 128];
  __syncthreads();
  if (tid < 64) {
    float v = partr[tid] + partr[tid + 64];
    v = waveAllSum(v);
    if (tid == 0) p.lossp[b] = v;
  }
}

// VO = V (complex) @ O (complex)
__global__ __launch_bounds__(256) void voprod_kernel(const float* __restrict__ vr,
                                                     const float* __restrict__ vi,
                                                     const float* __restrict__ orr,
                                                     const float* __restrict__ oii,
                                                     float* __restrict__ VOr,
                                                     float* __restrict__ VOi) {
  __shared__ float a_r[D], a_i[D];
  const int k = blockIdx.x;
  const int tid = threadIdx.x;
  if (tid < D) { a_r[tid] = vr[k * D + tid]; a_i[tid] = vi[k * D + tid]; }
  __syncthreads();
  const int m = tid & 127;
  const int half = tid >> 7;
  float acc = 0.f;
  if (half == 0) {
    #pragma unroll 8
    for (int jj = 0; jj < D; ++jj)
      acc += a_r[jj] * orr[jj * D + m] - a_i[jj] * oii[jj * D + m];
    VOr[k * D + m] = acc;
  } else {
    #pragma unroll 8
    for (int jj = 0; jj < D; ++jj)
      acc += a_r[jj] * oii[jj * D + m] + a_i[jj] * orr[jj * D + m];
    VOi[k * D + m] = acc;
  }
}

__global__ void vqprep_kernel(const float* __restrict__ cb_syn,
                              const float* __restrict__ cb_sem,
                              const float* __restrict__ adj_syn,
                              const float* __restrict__ adj_sem,
                              float* __restrict__ cbT_syn,
                              float* __restrict__ cbT_sem,
                              float* __restrict__ cnrm_syn,
                              float* __restrict__ cnrm_sem,
                              float* __restrict__ gbsig_syn,
                              float* __restrict__ gbsig_sem) {
  const int tid = blockIdx.x * 256 + threadIdx.x;
  const int nt = gridDim.x * 256;
  for (int e = tid; e < NSYN * D2; e += nt) {
    int c = e / D2, k = e % D2;
    cbT_syn[k * NSYN + c] = cb_syn[e];
  }
  for (int e = tid; e < NSEM * D2; e += nt) {
    int c = e / D2, k = e % D2;
    cbT_sem[k * NSEM + c] = cb_sem[e];
  }
  for (int c = tid; c < NSYN; c += nt) {
    float s = 0.f;
    for (int k = 0; k < D2; ++k) { float v = cb_syn[c * D2 + k]; s += v * v; }
    cnrm_syn[c] = s;
  }
  for (int c = tid; c < NSEM; c += nt) {
    float s = 0.f;
    for (int k = 0; k < D2; ++k) { float v = cb_sem[c * D2 + k]; s += v * v; }
    cnrm_sem[c] = s;
  }
  for (int e = tid; e < NSYN * NSYN; e += nt)
    gbsig_syn[e] = GB_C / (1.f + expf(-adj_syn[e]));
  for (int e = tid; e < NSEM * NSEM; e += nt)
    gbsig_sem[e] = GB_C / (1.f + expf(-adj_sem[e]));
}

// logits = X @ dec_W + dec_b
__global__ __launch_bounds__(256) void dec_kernel(const float* __restrict__ X,
                                                  const float* __restrict__ W,
                                                  const float* __restrict__ bias,
                                                  float* __restrict__ out) {
  __shared__ float A[32][D2];
  const int tid = threadIdx.x;
  const int bx = blockIdx.x;
  const int by = blockIdx.y;
  const float* xr = X + (size_t)by * 32 * D2;
  #pragma unroll
  for (int s = 0; s < 32; ++s) A[s][tid] = xr[s * D2 + tid];
  __syncthreads();
  const int ty = tid >> 5, tx = tid & 31;
  const int col0 = bx * 128 + tx * 4;
  const int r0 = ty * 4;
  float acc[4][4];
  #pragma unroll
  for (int r = 0; r < 4; ++r) {
    acc[r][0] = 0.f; acc[r][1] = 0.f; acc[r][2] = 0.f; acc[r][3] = 0.f;
  }
  const float* wp = W + col0;
  for (int k = 0; k < D2; k += 4) {
    float4 w0 = *(const float4*)(wp + (size_t)(k + 0) * VOC);
    float4 w1 = *(const float4*)(wp + (size_t)(k + 1) * VOC);
    float4 w2 = *(const float4*)(wp + (size_t)(k + 2) * VOC);
    float4 w3 = *(const float4*)(wp + (size_t)(k + 3) * VOC);
    #pragma unroll
    for (int r = 0; r < 4; ++r) {
      float4 a = *(const float4*)&A[r0 + r][k];
      acc[r][0] += a.x * w0.x + a.y * w1.x + a.z * w2.x + a.w * w3.x;
      acc[r][1] += a.x * w0.y + a.y * w1.y + a.z * w2.y + a.w * w3.y;
      acc[r][2] += a.x * w0.z + a.y * w1.z + a.z * w2.z + a.w * w3.z;
      acc[r][3] += a.x * w0.w + a.y * w1.w + a.z * w2.w + a.w * w3.w;
    }
  }
  float4 bv = *(const float4*)(bias + col0);
  #pragma unroll
  for (int r = 0; r < 4; ++r) {
    float4 o;
    o.x = acc[r][0] + bv.x; o.y = acc[r][1] + bv.y;
    o.z = acc[r][2] + bv.z; o.w = acc[r][3] + bv.w;
    *(float4*)(out + (size_t)(by * 32 + r0 + r) * VOC + col0) = o;
  }
}

__global__ void loss_kernel(const float* __restrict__ lp, float* __restrict__ out) {
  int l = threadIdx.x;
  float v = (l < BATCH) ? lp[l] : 0.f;
  #pragma unroll
  for (int off = 32; off; off >>= 1) v += __shfl_down(v, off);
  if (l == 0) out[0] = v * (1.25f / 8192.f);
}

extern "C" void kernel_launch(void* const* d_in, const int* in_sizes, int n_in,
                              void* d_out, int out_size, void* d_ws,
                              size_t ws_size, hipStream_t stream) {
  float* ws = (float*)d_ws;
  float* X = ws;                      // 1048576
  float* lossp = X + 1048576;         // 64
  float* VOr = lossp + 64;            // 16384
  float* VOi = VOr + 16384;           // 16384
  float* cbT_syn = VOi + 16384;       // 16384
  float* cbT_sem = cbT_syn + 16384;   // 32768
  float* cnrm_syn = cbT_sem + 32768;  // 64
  float* cnrm_sem = cnrm_syn + 64;    // 128
  float* gbsig_syn = cnrm_sem + 128;  // 4096
  float* gbsig_sem = gbsig_syn + 4096;// 16384

  RParams p;
  p.input_ids  = (const int*)d_in[0];
  p.prev_syn   = (const int*)d_in[1];
  p.prev_sem   = (const int*)d_in[2];
  p.emb_mag    = (const float*)d_in[3];
  p.emb_phase  = (const float*)d_in[4];
  p.cell_Wr    = (const float*)d_in[5];
  p.cell_Wi    = (const float*)d_in[6];
  p.norm_scale = (const float*)d_in[7];
  p.norm_shift = (const float*)d_in[8];
  p.modrelu_b  = (const float*)d_in[9];
  p.VOr        = VOr;
  p.VOi        = VOi;
  p.halt_W     = (const float*)d_in[18];
  p.halt_b     = (const float*)d_in[19];
  p.stk_W      = (const float*)d_in[20];
  p.stk_b      = (const float*)d_in[21];
  p.cb_syn     = (const float*)d_in[22];
  p.cb_sem     = (const float*)d_in[23];
  p.ctxsyn_W   = (const float*)d_in[24];
  p.ctxsyn_b   = (const float*)d_in[25];
  p.ctxsem_W   = (const float*)d_in[26];
  p.ctxsem_b   = (const float*)d_in[27];
  p.gate_W     = (const float*)d_in[30];
  p.gate_b     = (const float*)d_in[31];
  const float* dec_W = (const float*)d_in[32];
  const float* dec_b = (const float*)d_in[33];
  p.cbT_syn = cbT_syn;
  p.cbT_sem = cbT_sem;
  p.cnrm_syn = cnrm_syn;
  p.cnrm_sem = cnrm_sem;
  p.gbsig_syn = gbsig_syn;
  p.gbsig_sem = gbsig_sem;
  p.X = X;
  p.lossp = lossp;

  float* out = (float*)d_out;

  voprod_kernel<<<D, 256, 0, stream>>>((const float*)d_in[14], (const float*)d_in[15],
                                       (const float*)d_in[16], (const float*)d_in[17],
                                       VOr, VOi);
  vqprep_kernel<<<64, 256, 0, stream>>>((const float*)d_in[22], (const float*)d_in[23],
                                        (const float*)d_in[28], (const float*)d_in[29],
                                        cbT_syn, cbT_sem, cnrm_syn, cnrm_sem,
                                        gbsig_syn, gbsig_sem);
  recur_kernel<<<BATCH, 512, 0, stream>>>(p);
  dec_kernel<<<dim3(VOC / 128, BATCH * SEQ / 32), 256, 0, stream>>>(X, dec_W,
                                                                    dec_b, out);
  loss_kernel<<<1, 64, 0, stream>>>(lossp, out + (size_t)BATCH * SEQ * VOC);
}